// Round 1
// baseline (4965.574 us; speedup 1.0000x reference)
//
#include <hip/hip_runtime.h>

#define DDIM 768
#define NCLUST 3000
#define NROWS 65536
#define KSP 128
#define MAXL 8192

// ---------------- K0: zero best[] and dis slot ----------------
__global__ __launch_bounds__(256) void k0_init(unsigned long long* __restrict__ best,
                                               float* __restrict__ dis_slot) {
  int i = blockIdx.x * 256 + threadIdx.x;
  if (i < NROWS) best[i] = 0ull;
  if (i == 0) *dis_slot = 0.0f;
}

// ---------------- K1: fused f32 GEMM (x @ mu^T) + row argmax -------------
// 64x64 tile, BK=16, 256 threads, 4x4 micro-tile per thread.
// Packs (monotone f32 key << 32) | ~col into u64; atomicMax per row.
// Tie on sim -> larger ~col wins -> smaller col index (matches jnp.argmax).
__global__ __launch_bounds__(256) void k1_gemm_argmax(const float* __restrict__ X,
                                                      const float* __restrict__ MU,
                                                      unsigned long long* __restrict__ best) {
  __shared__ float As[16][64];
  __shared__ float Bs[16][64];
  const int m0 = blockIdx.x * 64;
  const int n0 = blockIdx.y * 64;
  const int t  = threadIdx.x;
  const int tx = t & 15, ty = t >> 4;
  const int lrow = t >> 2, lcg = t & 3;

  float acc[4][4];
#pragma unroll
  for (int i = 0; i < 4; ++i)
#pragma unroll
    for (int jj = 0; jj < 4; ++jj) acc[i][jj] = 0.0f;

  const float* aptr = X + (size_t)(m0 + lrow) * DDIM + lcg * 4;
  const bool bvalid = (n0 + lrow) < NCLUST;
  const float* bptr = MU + (size_t)(bvalid ? (n0 + lrow) : 0) * DDIM + lcg * 4;

  for (int k0 = 0; k0 < DDIM; k0 += 16) {
    float4 av = *reinterpret_cast<const float4*>(aptr + k0);
    float4 bv = make_float4(0.f, 0.f, 0.f, 0.f);
    if (bvalid) bv = *reinterpret_cast<const float4*>(bptr + k0);
    As[lcg * 4 + 0][lrow] = av.x; As[lcg * 4 + 1][lrow] = av.y;
    As[lcg * 4 + 2][lrow] = av.z; As[lcg * 4 + 3][lrow] = av.w;
    Bs[lcg * 4 + 0][lrow] = bv.x; Bs[lcg * 4 + 1][lrow] = bv.y;
    Bs[lcg * 4 + 2][lrow] = bv.z; Bs[lcg * 4 + 3][lrow] = bv.w;
    __syncthreads();
#pragma unroll
    for (int kk = 0; kk < 16; ++kk) {
      float4 af = *reinterpret_cast<const float4*>(&As[kk][ty * 4]);
      float4 bf = *reinterpret_cast<const float4*>(&Bs[kk][tx * 4]);
      float a[4] = {af.x, af.y, af.z, af.w};
      float b[4] = {bf.x, bf.y, bf.z, bf.w};
#pragma unroll
      for (int i = 0; i < 4; ++i)
#pragma unroll
        for (int jj = 0; jj < 4; ++jj)
          acc[i][jj] = fmaf(a[i], b[jj], acc[i][jj]);
    }
    __syncthreads();
  }

  // epilogue: per-row argmax over this 64-col tile, reduce across tx lanes
#pragma unroll
  for (int i = 0; i < 4; ++i) {
    unsigned long long bk = 0ull;
#pragma unroll
    for (int jj = 0; jj < 4; ++jj) {
      int col = n0 + tx * 4 + jj;
      if (col < NCLUST) {
        unsigned ub = __float_as_uint(acc[i][jj]);
        unsigned key = (ub & 0x80000000u) ? ~ub : (ub | 0x80000000u);
        unsigned long long pk =
            ((unsigned long long)key << 32) | (unsigned)(~(unsigned)col);
        if (pk > bk) bk = pk;
      }
    }
    // lanes within a wave: lane = (ty&3)*16 + tx -> xor over tx bits 0..3
#pragma unroll
    for (int s = 1; s < 16; s <<= 1) {
      unsigned long long o = __shfl_xor(bk, s, 64);
      if (o > bk) bk = o;
    }
    if (tx == 0) atomicMax(&best[m0 + ty * 4 + i], bk);
  }
}

// ---------------- K2: decode assignment ----------------
__global__ __launch_bounds__(256) void k2_decode(const unsigned long long* __restrict__ best,
                                                 int* __restrict__ r) {
  int i = blockIdx.x * 256 + threadIdx.x;
  if (i < NROWS) r[i] = (int)(~(unsigned)(best[i] & 0xffffffffull));
}

// ---------------- K3: per-cluster finalize ----------------
// Ordered member list (ascending row idx) -> deterministic f32 sums matching
// numpy segment_sum order; EMA + normalize + exact radix-select top-k + dis.
__global__ __launch_bounds__(256) void k3_finalize(const float* __restrict__ X,
                                                   const float* __restrict__ MU,
                                                   const int* __restrict__ r,
                                                   float* __restrict__ out,
                                                   float* __restrict__ dis_slot) {
#pragma clang fp contract(off)
  const int j = blockIdx.x;
  const int t = threadIdx.x;
  const int lane = t & 63;
  const int wid = t >> 6;
  __shared__ int list[MAXL];
  __shared__ int wcnt[4];
  __shared__ float red[4];
  __shared__ unsigned hist[256];
  __shared__ unsigned selv;
  __shared__ int seln;

  // ---- ordered member scan (ascending row index) ----
  int cnt = 0;
  for (int base = 0; base < NROWS; base += 256) {
    int i = base + t;
    bool flag = (r[i] == j);
    unsigned long long bm = __ballot(flag);
    if (lane == 0) wcnt[wid] = __popcll(bm);
    __syncthreads();
    int off = cnt;
    for (int w = 0; w < wid; ++w) off += wcnt[w];
    if (flag) {
      int pos = off + __popcll(bm & ((1ull << lane) - 1ull));
      if (pos < MAXL) list[pos] = i;
    }
    cnt += wcnt[0] + wcnt[1] + wcnt[2] + wcnt[3];
    __syncthreads();
  }
  int cl = cnt < MAXL ? cnt : MAXL;

  // ---- deterministic ordered sums; each thread owns dims t, t+256, t+512 ----
  float s0 = 0.f, s1 = 0.f, s2 = 0.f;
  for (int m = 0; m < cl; ++m) {
    const float* xr = X + (size_t)list[m] * DDIM;
    s0 += xr[t];
    s1 += xr[t + 256];
    s2 += xr[t + 512];
  }
  const float mu0 = MU[(size_t)j * DDIM + t];
  const float mu1 = MU[(size_t)j * DDIM + t + 256];
  const float mu2 = MU[(size_t)j * DDIM + t + 512];
  // mimic np: segment sum includes mu row appended last, then x_last (=mu) subtracted
  s0 = s0 + mu0; s1 = s1 + mu1; s2 = s2 + mu2;
  s0 = s0 - mu0; s1 = s1 - mu1; s2 = s2 - mu2;

  float u0, u1, u2;
  if (cnt >= 1) {
    float c = (float)cnt;
    u0 = s0 / c; u1 = s1 / c; u2 = s2 / c;
  } else {
    u0 = mu0; u1 = mu1; u2 = mu2;
  }
  float v0 = u0 * 0.2f + mu0 * 0.8f;
  float v1 = u1 * 0.2f + mu1 * 0.8f;
  float v2 = u2 * 0.2f + mu2 * 0.8f;

  // ---- norm ----
  float ss = v0 * v0 + v1 * v1 + v2 * v2;
#pragma unroll
  for (int s = 32; s > 0; s >>= 1) ss += __shfl_down(ss, s, 64);
  if (lane == 0) red[wid] = ss;
  __syncthreads();
  float tot = red[0] + red[1] + red[2] + red[3];
  float den = sqrtf(tot);
  den = fmaxf(den, 1e-12f);
  float un0 = v0 / den, un1 = v1 / den, un2 = v2 / den;
  unsigned k0b = __float_as_uint(fabsf(un0));
  unsigned k1b = __float_as_uint(fabsf(un1));
  unsigned k2b = __float_as_uint(fabsf(un2));
  __syncthreads();  // red[] will be reused for dist

  // ---- exact 128th-largest |u| via 4-round radix select on bit patterns ----
  unsigned cur = 0;
  int need = KSP;
  for (int sh = 24; sh >= 0; sh -= 8) {
    hist[t] = 0u;
    __syncthreads();
    bool m0_ = (sh == 24) || ((k0b >> (sh + 8)) == (cur >> (sh + 8)));
    bool m1_ = (sh == 24) || ((k1b >> (sh + 8)) == (cur >> (sh + 8)));
    bool m2_ = (sh == 24) || ((k2b >> (sh + 8)) == (cur >> (sh + 8)));
    if (m0_) atomicAdd(&hist[(k0b >> sh) & 255u], 1u);
    if (m1_) atomicAdd(&hist[(k1b >> sh) & 255u], 1u);
    if (m2_) atomicAdd(&hist[(k2b >> sh) & 255u], 1u);
    __syncthreads();
    if (t == 0) {
      unsigned cum = 0;
      int b = 255;
      for (; b >= 0; --b) {
        cum += hist[b];
        if ((int)cum >= need) break;
      }
      if (b < 0) b = 0;  // unreachable by invariant
      selv = (unsigned)b;
      seln = need - (int)(cum - hist[b]);
    }
    __syncthreads();
    cur |= (selv << sh);
    need = seln;
  }
  unsigned th = cur;

  // ---- sparsify, write out, distance ----
  float o0 = (k0b >= th) ? un0 : 0.0f;
  float o1 = (k1b >= th) ? un1 : 0.0f;
  float o2 = (k2b >= th) ? un2 : 0.0f;
  out[(size_t)j * DDIM + t] = o0;
  out[(size_t)j * DDIM + t + 256] = o1;
  out[(size_t)j * DDIM + t + 512] = o2;

  float q0 = o0 - mu0, q1 = o1 - mu1, q2 = o2 - mu2;
  float dq = q0 * q0 + q1 * q1 + q2 * q2;
#pragma unroll
  for (int s = 32; s > 0; s >>= 1) dq += __shfl_down(dq, s, 64);
  __syncthreads();  // protect red[] from previous use
  if (lane == 0) red[wid] = dq;
  __syncthreads();
  if (t == 0) {
    float dtot = red[0] + red[1] + red[2] + red[3];
    float dn = sqrtf(dtot);
    atomicMax((unsigned*)dis_slot, __float_as_uint(dn));
  }
}

extern "C" void kernel_launch(void* const* d_in, const int* in_sizes, int n_in,
                              void* d_out, int out_size, void* d_ws, size_t ws_size,
                              hipStream_t stream) {
  const float* X = (const float*)d_in[0];
  const float* MU = (const float*)d_in[1];
  float* out = (float*)d_out;
  float* dis_slot = out + (size_t)NCLUST * DDIM;

  unsigned long long* best = (unsigned long long*)d_ws;
  int* r = (int*)((char*)d_ws + (size_t)NROWS * sizeof(unsigned long long));

  k0_init<<<NROWS / 256, 256, 0, stream>>>(best, dis_slot);
  dim3 g1(NROWS / 64, (NCLUST + 63) / 64);
  k1_gemm_argmax<<<g1, 256, 0, stream>>>(X, MU, best);
  k2_decode<<<NROWS / 256, 256, 0, stream>>>(best, r);
  k3_finalize<<<NCLUST, 256, 0, stream>>>(X, MU, r, out, dis_slot);
}

// Round 2
// 2329.947 us; speedup vs baseline: 2.1312x; 2.1312x over previous
//
#include <hip/hip_runtime.h>
#include <hip/hip_bf16.h>

#define M 65536
#define N 3000
#define NPAD 3072
#define K 768
#define KA 1536      // A2 physical K: [hx | lx]
#define KB 2304      // B2 physical K: [hy | ly | hy]
#define NTIL 24      // 3072 / 128
#define KSP 128
#define MAXL 8192
#define GAPTHR 2e-3f
#define MAXAMB 4096

typedef __attribute__((ext_vector_type(8))) short bf16x8;
typedef __attribute__((ext_vector_type(4))) float f32x4;
typedef unsigned long long u64;
typedef unsigned int u32;

#define AS1 __attribute__((address_space(1)))
#define AS3 __attribute__((address_space(3)))

// ws layout (bytes)
#define OFF_A2   0ull
#define OFF_B2   201326592ull
#define OFF_GTOP 215482368ull
#define OFF_R    240648192ull
#define OFF_AMB  240910336ull
#define OFF_CNT  240926720ull
#define WS_NEED  240926976ull

__device__ inline unsigned short f2bf(float x) {
  __hip_bfloat16 h = __float2bfloat16(x);
  return *reinterpret_cast<unsigned short*>(&h);
}
__device__ inline float bf2f(unsigned short u) {
  __hip_bfloat16 h;
  *reinterpret_cast<unsigned short*>(&h) = u;
  return __bfloat162float(h);
}
__device__ inline u32 fkey(float v) {
  u32 ub = __float_as_uint(v);
  return (ub & 0x80000000u) ? ~ub : (ub | 0x80000000u);
}
__device__ inline float keyf(u32 key) {
  u32 ub = (key & 0x80000000u) ? (key ^ 0x80000000u) : ~key;
  return __uint_as_float(ub);
}
__device__ inline void gload16(const void* g, void* l) {
  __builtin_amdgcn_global_load_lds((AS1 u32*)g, (AS3 u32*)l, 16, 0, 0);
}

// ---------------- K0a: X -> bf16 hi/lo ----------------
__global__ __launch_bounds__(256) void k_convx(const float* __restrict__ X,
                                               unsigned short* __restrict__ A2) {
  const int tot = M * (K / 4);
  for (int i = blockIdx.x * 256 + threadIdx.x; i < tot; i += gridDim.x * 256) {
    int row = i / (K / 4);
    int c4 = (i - row * (K / 4)) * 4;
    float4 v = *reinterpret_cast<const float4*>(X + (size_t)row * K + c4);
    ushort4 h, l;
    h.x = f2bf(v.x); l.x = f2bf(v.x - bf2f(h.x));
    h.y = f2bf(v.y); l.y = f2bf(v.y - bf2f(h.y));
    h.z = f2bf(v.z); l.z = f2bf(v.z - bf2f(h.z));
    h.w = f2bf(v.w); l.w = f2bf(v.w - bf2f(h.w));
    *reinterpret_cast<ushort4*>(A2 + (size_t)row * KA + c4) = h;
    *reinterpret_cast<ushort4*>(A2 + (size_t)row * KA + 768 + c4) = l;
  }
}

// ---------------- K0b: MU -> bf16 [hy|ly|hy], pad rows zero; reset counters --
__global__ __launch_bounds__(256) void k_convmu(const float* __restrict__ MU,
                                                unsigned short* __restrict__ B2,
                                                u32* __restrict__ ambCnt,
                                                float* __restrict__ dis_slot) {
  int j = blockIdx.x, t = threadIdx.x;
  if (j == 0 && t == 0) *ambCnt = 0u;
  if (j == 0 && t == 1) *dis_slot = 0.0f;
  for (int c = t; c < K; c += 256) {
    float x = (j < N) ? MU[(size_t)j * K + c] : 0.0f;
    unsigned short h = f2bf(x);
    unsigned short l = f2bf(x - bf2f(h));
    B2[(size_t)j * KB + c] = h;
    B2[(size_t)j * KB + 768 + c] = l;
    B2[(size_t)j * KB + 1536 + c] = h;
  }
}

// ---------------- K1: bf16x2-split MFMA GEMM + per-tile top2 epilogue -------
__global__ __launch_bounds__(256) void k_gemm(const unsigned short* __restrict__ A2,
                                              const unsigned short* __restrict__ B2,
                                              u64* __restrict__ gtop) {
  __shared__ unsigned short As[128 * 32];
  __shared__ unsigned short Bs[128 * 32];
  __shared__ u64 stop[2][128][2];

  // XCD-chunked swizzle: xcd owns 64 m-panels; groups of 4 m-panels x 24 n.
  const int bid = blockIdx.x;
  const int xcd = bid & 7, lt = bid >> 3;
  const int g = lt / 96, rem = lt % 96;
  const int nt = rem >> 2, mi = rem & 3;
  const int mt = xcd * 64 + g * 4 + mi;
  const int m0 = mt * 128, n0 = nt * 128;

  const int t = threadIdx.x;
  const int w = t >> 6, ln = t & 63;
  const int wr = w >> 1, wc = w & 1;
  const int lg = ln >> 4, li = ln & 15;

  f32x4 acc[4][4] = {};

  const int ar = t >> 2;        // staging row within tile (0..63)
  const int ac = (t & 3) * 8;   // staging col (bf16 elems)

  for (int k = 0; k < KB; k += 32) {
    int ka0 = (k < 768) ? k : (k - 768);
    const unsigned short* ga0 = A2 + (size_t)(m0 + ar) * KA + ka0 + ac;
    const unsigned short* gb0 = B2 + (size_t)(n0 + ar) * KB + k + ac;
    gload16(ga0, As + w * 512);
    gload16(ga0 + (size_t)64 * KA, As + 2048 + w * 512);
    gload16(gb0, Bs + w * 512);
    gload16(gb0 + (size_t)64 * KB, Bs + 2048 + w * 512);
    __syncthreads();
    bf16x8 a[4], b[4];
#pragma unroll
    for (int m = 0; m < 4; ++m)
      a[m] = *reinterpret_cast<const bf16x8*>(As + (wr * 64 + m * 16 + li) * 32 + lg * 8);
#pragma unroll
    for (int n = 0; n < 4; ++n)
      b[n] = *reinterpret_cast<const bf16x8*>(Bs + (wc * 64 + n * 16 + li) * 32 + lg * 8);
#pragma unroll
    for (int m = 0; m < 4; ++m)
#pragma unroll
      for (int n = 0; n < 4; ++n)
        acc[m][n] = __builtin_amdgcn_mfma_f32_16x16x32_bf16(a[m], b[n], acc[m][n], 0, 0, 0);
    __syncthreads();
  }

  // epilogue: per-row (top1, top2) over this block's 128 cols
#pragma unroll
  for (int m = 0; m < 4; ++m)
#pragma unroll
    for (int reg = 0; reg < 4; ++reg) {
      u64 b1 = 0, b2 = 0;
#pragma unroll
      for (int n = 0; n < 4; ++n) {
        int col = n0 + wc * 64 + n * 16 + li;
        if (col < N) {
          u64 pk = ((u64)fkey(acc[m][n][reg]) << 32) | (u32)(~(u32)col);
          if (pk > b1) { b2 = b1; b1 = pk; }
          else if (pk > b2) b2 = pk;
        }
      }
#pragma unroll
      for (int s = 1; s < 16; s <<= 1) {
        u64 o1 = __shfl_xor((unsigned long long)b1, s, 64);
        u64 o2 = __shfl_xor((unsigned long long)b2, s, 64);
        u64 n1 = b1 > o1 ? b1 : o1;
        u64 lo = b1 > o1 ? o1 : b1;
        u64 mx = b2 > o2 ? b2 : o2;
        b2 = lo > mx ? lo : mx;
        b1 = n1;
      }
      if (li == 0) {
        int rloc = wr * 64 + m * 16 + lg * 4 + reg;
        stop[wc][rloc][0] = b1;
        stop[wc][rloc][1] = b2;
      }
    }
  __syncthreads();
  if (t < 128) {
    u64 a1 = stop[0][t][0], a2 = stop[0][t][1];
    u64 c1 = stop[1][t][0], c2 = stop[1][t][1];
    u64 g1 = a1 > c1 ? a1 : c1;
    u64 lo = a1 > c1 ? c1 : a1;
    u64 mx = a2 > c2 ? a2 : c2;
    u64 g2 = lo > mx ? lo : mx;
    u64* dst = gtop + ((size_t)(m0 + t) * NTIL + nt) * 2;
    dst[0] = g1;
    dst[1] = g2;
  }
}

// ---------------- K2: merge 24 tiles -> r, flag ambiguous rows ----------------
__global__ __launch_bounds__(256) void k_reduce(const u64* __restrict__ gtop,
                                                int* __restrict__ r,
                                                int* __restrict__ amb,
                                                u32* __restrict__ ambCnt) {
  int row = blockIdx.x * 256 + threadIdx.x;
  if (row >= M) return;
  const u64* src = gtop + (size_t)row * NTIL * 2;
  u64 g1 = 0, g2 = 0;
  for (int tt = 0; tt < NTIL; ++tt) {
    u64 a1 = src[tt * 2], a2 = src[tt * 2 + 1];
    u64 n1 = g1 > a1 ? g1 : a1;
    u64 lo = g1 > a1 ? a1 : g1;
    u64 mx = g2 > a2 ? g2 : a2;
    g2 = lo > mx ? lo : mx;
    g1 = n1;
  }
  r[row] = (int)(~(u32)(g1 & 0xffffffffull));
  float v1 = keyf((u32)(g1 >> 32)), v2 = keyf((u32)(g2 >> 32));
  if (v1 - v2 < GAPTHR) {
    u32 idx = atomicAdd(ambCnt, 1u);
    if (idx < MAXAMB) amb[idx] = row;
  }
}

// ---------------- K3: exact fp32 re-argmax for ambiguous rows ----------------
__global__ __launch_bounds__(256) void k_refine(const float* __restrict__ X,
                                                const float* __restrict__ MU,
                                                const u64* __restrict__ gtop,
                                                const int* __restrict__ amb,
                                                const u32* __restrict__ ambCnt,
                                                int* __restrict__ r) {
  __shared__ float xrow[768];
  __shared__ u64 wbest[4];
  __shared__ float vmax_s;
  int t = threadIdx.x, w = t >> 6, ln = t & 63;
  int n_amb = (int)min(*ambCnt, (u32)MAXAMB);
  for (int ai = blockIdx.x; ai < n_amb; ai += gridDim.x) {
    int row = amb[ai];
    xrow[t] = X[(size_t)row * K + t];
    xrow[t + 256] = X[(size_t)row * K + t + 256];
    xrow[t + 512] = X[(size_t)row * K + t + 512];
    if (t == 0) {
      float vm = -1e30f;
      for (int tt = 0; tt < NTIL; ++tt)
        vm = fmaxf(vm, keyf((u32)(gtop[((size_t)row * NTIL + tt) * 2] >> 32)));
      vmax_s = vm;
    }
    __syncthreads();
    u64 best = 0;
    for (int tile = 0; tile < NTIL; ++tile) {
      float tb = keyf((u32)(gtop[((size_t)row * NTIL + tile) * 2] >> 32));
      if (tb < vmax_s - GAPTHR) continue;
      for (int q = 0; q < 32; ++q) {
        int c = tile * 128 + w * 32 + q;
        if (c >= N) break;
        float p = 0.0f;
        for (int d = ln; d < K; d += 64) p += xrow[d] * MU[(size_t)c * K + d];
#pragma unroll
        for (int s = 32; s; s >>= 1) p += __shfl_xor(p, s, 64);
        u64 pk = ((u64)fkey(p) << 32) | (u32)(~(u32)c);
        if (pk > best) best = pk;
      }
    }
    if (ln == 0) wbest[w] = best;
    __syncthreads();
    if (t == 0) {
      u64 b = wbest[0];
      for (int i = 1; i < 4; ++i)
        if (wbest[i] > b) b = wbest[i];
      r[row] = (int)(~(u32)(b & 0xffffffffull));
    }
    __syncthreads();
  }
}

// ---------------- K4: per-cluster finalize (verified in R1) ----------------
__global__ __launch_bounds__(256) void k_finalize(const float* __restrict__ X,
                                                  const float* __restrict__ MU,
                                                  const int* __restrict__ r,
                                                  float* __restrict__ out,
                                                  float* __restrict__ dis_slot) {
#pragma clang fp contract(off)
  const int j = blockIdx.x;
  const int t = threadIdx.x;
  const int lane = t & 63;
  const int wid = t >> 6;
  __shared__ int list[MAXL];
  __shared__ int wcnt[4];
  __shared__ float red[4];
  __shared__ unsigned hist[256];
  __shared__ unsigned selv;
  __shared__ int seln;

  int cnt = 0;
  for (int base = 0; base < M; base += 256) {
    int i = base + t;
    bool flag = (r[i] == j);
    unsigned long long bm = __ballot(flag);
    if (lane == 0) wcnt[wid] = __popcll(bm);
    __syncthreads();
    int off = cnt;
    for (int ww = 0; ww < wid; ++ww) off += wcnt[ww];
    if (flag) {
      int pos = off + __popcll(bm & ((1ull << lane) - 1ull));
      if (pos < MAXL) list[pos] = i;
    }
    cnt += wcnt[0] + wcnt[1] + wcnt[2] + wcnt[3];
    __syncthreads();
  }
  int cl = cnt < MAXL ? cnt : MAXL;

  float s0 = 0.f, s1 = 0.f, s2 = 0.f;
  for (int m = 0; m < cl; ++m) {
    const float* xr = X + (size_t)list[m] * K;
    s0 += xr[t];
    s1 += xr[t + 256];
    s2 += xr[t + 512];
  }
  const float mu0 = MU[(size_t)j * K + t];
  const float mu1 = MU[(size_t)j * K + t + 256];
  const float mu2 = MU[(size_t)j * K + t + 512];
  s0 = s0 + mu0; s1 = s1 + mu1; s2 = s2 + mu2;
  s0 = s0 - mu0; s1 = s1 - mu1; s2 = s2 - mu2;

  float u0, u1, u2;
  if (cnt >= 1) {
    float c = (float)cnt;
    u0 = s0 / c; u1 = s1 / c; u2 = s2 / c;
  } else {
    u0 = mu0; u1 = mu1; u2 = mu2;
  }
  float v0 = u0 * 0.2f + mu0 * 0.8f;
  float v1 = u1 * 0.2f + mu1 * 0.8f;
  float v2 = u2 * 0.2f + mu2 * 0.8f;

  float ss = v0 * v0 + v1 * v1 + v2 * v2;
#pragma unroll
  for (int s = 32; s > 0; s >>= 1) ss += __shfl_down(ss, s, 64);
  if (lane == 0) red[wid] = ss;
  __syncthreads();
  float tot = red[0] + red[1] + red[2] + red[3];
  float den = sqrtf(tot);
  den = fmaxf(den, 1e-12f);
  float un0 = v0 / den, un1 = v1 / den, un2 = v2 / den;
  unsigned k0b = __float_as_uint(fabsf(un0));
  unsigned k1b = __float_as_uint(fabsf(un1));
  unsigned k2b = __float_as_uint(fabsf(un2));
  __syncthreads();

  unsigned cur = 0;
  int need = KSP;
  for (int sh = 24; sh >= 0; sh -= 8) {
    hist[t] = 0u;
    __syncthreads();
    bool m0_ = (sh == 24) || ((k0b >> (sh + 8)) == (cur >> (sh + 8)));
    bool m1_ = (sh == 24) || ((k1b >> (sh + 8)) == (cur >> (sh + 8)));
    bool m2_ = (sh == 24) || ((k2b >> (sh + 8)) == (cur >> (sh + 8)));
    if (m0_) atomicAdd(&hist[(k0b >> sh) & 255u], 1u);
    if (m1_) atomicAdd(&hist[(k1b >> sh) & 255u], 1u);
    if (m2_) atomicAdd(&hist[(k2b >> sh) & 255u], 1u);
    __syncthreads();
    if (t == 0) {
      unsigned cum = 0;
      int b = 255;
      for (; b >= 0; --b) {
        cum += hist[b];
        if ((int)cum >= need) break;
      }
      if (b < 0) b = 0;
      selv = (unsigned)b;
      seln = need - (int)(cum - hist[b]);
    }
    __syncthreads();
    cur |= (selv << sh);
    need = seln;
  }
  unsigned th = cur;

  float o0 = (k0b >= th) ? un0 : 0.0f;
  float o1 = (k1b >= th) ? un1 : 0.0f;
  float o2 = (k2b >= th) ? un2 : 0.0f;
  out[(size_t)j * K + t] = o0;
  out[(size_t)j * K + t + 256] = o1;
  out[(size_t)j * K + t + 512] = o2;

  float q0 = o0 - mu0, q1 = o1 - mu1, q2 = o2 - mu2;
  float dq = q0 * q0 + q1 * q1 + q2 * q2;
#pragma unroll
  for (int s = 32; s > 0; s >>= 1) dq += __shfl_down(dq, s, 64);
  __syncthreads();
  if (lane == 0) red[wid] = dq;
  __syncthreads();
  if (t == 0) {
    float dtot = red[0] + red[1] + red[2] + red[3];
    float dn = sqrtf(dtot);
    atomicMax((unsigned*)dis_slot, __float_as_uint(dn));
  }
}

// ================= fallback fp32 path (ws too small) =================
__global__ __launch_bounds__(256) void k0_init(u64* __restrict__ best,
                                               float* __restrict__ dis_slot) {
  int i = blockIdx.x * 256 + threadIdx.x;
  if (i < M) best[i] = 0ull;
  if (i == 0) *dis_slot = 0.0f;
}

__global__ __launch_bounds__(256) void k1_f32(const float* __restrict__ X,
                                              const float* __restrict__ MU,
                                              u64* __restrict__ best) {
  __shared__ float Asf[16][64];
  __shared__ float Bsf[16][64];
  const int m0 = blockIdx.x * 64;
  const int n0 = blockIdx.y * 64;
  const int t = threadIdx.x;
  const int tx = t & 15, ty = t >> 4;
  const int lrow = t >> 2, lcg = t & 3;

  float acc[4][4];
#pragma unroll
  for (int i = 0; i < 4; ++i)
#pragma unroll
    for (int jj = 0; jj < 4; ++jj) acc[i][jj] = 0.0f;

  const float* aptr = X + (size_t)(m0 + lrow) * K + lcg * 4;
  const bool bvalid = (n0 + lrow) < N;
  const float* bptr = MU + (size_t)(bvalid ? (n0 + lrow) : 0) * K + lcg * 4;

  for (int k0 = 0; k0 < K; k0 += 16) {
    float4 av = *reinterpret_cast<const float4*>(aptr + k0);
    float4 bv = make_float4(0.f, 0.f, 0.f, 0.f);
    if (bvalid) bv = *reinterpret_cast<const float4*>(bptr + k0);
    Asf[lcg * 4 + 0][lrow] = av.x; Asf[lcg * 4 + 1][lrow] = av.y;
    Asf[lcg * 4 + 2][lrow] = av.z; Asf[lcg * 4 + 3][lrow] = av.w;
    Bsf[lcg * 4 + 0][lrow] = bv.x; Bsf[lcg * 4 + 1][lrow] = bv.y;
    Bsf[lcg * 4 + 2][lrow] = bv.z; Bsf[lcg * 4 + 3][lrow] = bv.w;
    __syncthreads();
#pragma unroll
    for (int kk = 0; kk < 16; ++kk) {
      float4 af = *reinterpret_cast<const float4*>(&Asf[kk][ty * 4]);
      float4 bf = *reinterpret_cast<const float4*>(&Bsf[kk][tx * 4]);
      float a[4] = {af.x, af.y, af.z, af.w};
      float b[4] = {bf.x, bf.y, bf.z, bf.w};
#pragma unroll
      for (int i = 0; i < 4; ++i)
#pragma unroll
        for (int jj = 0; jj < 4; ++jj)
          acc[i][jj] = fmaf(a[i], b[jj], acc[i][jj]);
    }
    __syncthreads();
  }
#pragma unroll
  for (int i = 0; i < 4; ++i) {
    u64 bk = 0ull;
#pragma unroll
    for (int jj = 0; jj < 4; ++jj) {
      int col = n0 + tx * 4 + jj;
      if (col < N) {
        u64 pk = ((u64)fkey(acc[i][jj]) << 32) | (u32)(~(u32)col);
        if (pk > bk) bk = pk;
      }
    }
#pragma unroll
    for (int s = 1; s < 16; s <<= 1) {
      u64 o = __shfl_xor((unsigned long long)bk, s, 64);
      if (o > bk) bk = o;
    }
    if (tx == 0) atomicMax(&best[m0 + ty * 4 + i], bk);
  }
}

__global__ __launch_bounds__(256) void k2_decode(const u64* __restrict__ best,
                                                 int* __restrict__ r) {
  int i = blockIdx.x * 256 + threadIdx.x;
  if (i < M) r[i] = (int)(~(u32)(best[i] & 0xffffffffull));
}

extern "C" void kernel_launch(void* const* d_in, const int* in_sizes, int n_in,
                              void* d_out, int out_size, void* d_ws, size_t ws_size,
                              hipStream_t stream) {
  const float* X = (const float*)d_in[0];
  const float* MU = (const float*)d_in[1];
  float* out = (float*)d_out;
  float* dis_slot = out + (size_t)N * K;

  if (ws_size >= WS_NEED) {
    unsigned short* A2 = (unsigned short*)((char*)d_ws + OFF_A2);
    unsigned short* B2 = (unsigned short*)((char*)d_ws + OFF_B2);
    u64* gtop = (u64*)((char*)d_ws + OFF_GTOP);
    int* r = (int*)((char*)d_ws + OFF_R);
    int* amb = (int*)((char*)d_ws + OFF_AMB);
    u32* ambCnt = (u32*)((char*)d_ws + OFF_CNT);

    k_convx<<<8192, 256, 0, stream>>>(X, A2);
    k_convmu<<<NPAD, 256, 0, stream>>>(MU, B2, ambCnt, dis_slot);
    k_gemm<<<512 * NTIL, 256, 0, stream>>>(A2, B2, gtop);
    k_reduce<<<M / 256, 256, 0, stream>>>(gtop, r, amb, ambCnt);
    k_refine<<<256, 256, 0, stream>>>(X, MU, gtop, amb, ambCnt, r);
    k_finalize<<<N, 256, 0, stream>>>(X, MU, r, out, dis_slot);
  } else {
    u64* best = (u64*)d_ws;
    int* r = (int*)((char*)d_ws + (size_t)M * sizeof(u64));
    k0_init<<<M / 256, 256, 0, stream>>>(best, dis_slot);
    dim3 g1(M / 64, (N + 63) / 64);
    k1_f32<<<g1, 256, 0, stream>>>(X, MU, best);
    k2_decode<<<M / 256, 256, 0, stream>>>(best, r);
    k_finalize<<<N, 256, 0, stream>>>(X, MU, r, out, dis_slot);
  }
}